// Round 8
// baseline (431.996 us; speedup 1.0000x reference)
//
#include <hip/hip_runtime.h>

#define N_PTS 131072
#define K_CODES 1024
#define DIM 64
#define DECAYF 0.99f
#define OMDF 0.01f
#define EPSF 1e-5f

// ---- d_out layout (float elements, reference return order) ----
#define OUT_ZQ      0                  // [N, D]
#define OUT_LOSS    8388608            // scalar
#define OUT_IDX     8388609            // [N] (indices as floats)
#define OUT_NEWEMB  8519681            // [K, D]
#define OUT_NEWCS   8585217            // [K]
#define OUT_NEWEMA  8586241            // [K, D]

// ---- ws layout (float elements) ----
// zero region: [0, WS_ZERO_END) — zeroed by econv blocks 4..35
#define WS_C8       0                  // 8*K floats
#define WS_ACNT     8192               // 16 ints
#define WS_LOSS     8208               // 16 floats
#define WS_EMBSUM   8224               // K*D floats (atomic accumulator)
#define WS_ZERO_END 73760
#define WS_ENORM    73760              // K
#define WS_CUR8     74784              // 8*K ints
#define WS_CS       82976              // K
#define WS_AMBIG    84000              // N ints
#define WS_ORDER    215072             // N ints (packed code<<17|row)
#define WS_E2       346144             // K*128 bf16 (32768 float slots); byte off %16==0

typedef __attribute__((ext_vector_type(8))) short bf16x8;
typedef __attribute__((ext_vector_type(4))) float f32x4;

static __device__ inline short f2bf(float f) {
    unsigned u = __float_as_uint(f);
    unsigned r = (u + 0x7fffu + ((u >> 16) & 1u)) >> 16;   // RNE
    return (short)r;
}
static __device__ inline float bf2f(short h) {
    return __uint_as_float(((unsigned)(unsigned short)h) << 16);
}

// blocks 0..3: E -> E2 = bf16 hi/lo split of (-2E), [hi(64)|lo(64)]; enorm.
// blocks 4..35: zero the ws counter/accumulator region (replaces memset).
__global__ __launch_bounds__(256) void econv_kernel(const float* __restrict__ E,
                                                    short* __restrict__ E2,
                                                    float* __restrict__ enorm,
                                                    float* __restrict__ ws0) {
    if (blockIdx.x >= 4) {
        for (int i = (blockIdx.x - 4) * 256 + threadIdx.x; i < WS_ZERO_END;
             i += 32 * 256)
            ws0[i] = 0.f;
        return;
    }
    int k = blockIdx.x * 256 + threadIdx.x;
    const float* ep = E + (size_t)k * DIM;
    short* o = E2 + (size_t)k * 128;
    float s = 0.f;
#pragma unroll
    for (int d = 0; d < 64; ++d) {
        float f = ep[d];
        s += f * f;
        float m = -2.f * f;
        short h = f2bf(m);
        o[d] = h;
        o[64 + d] = f2bf(m - bf2f(h));
    }
    enorm[k] = s;
}

// 2048 blocks x 256 thr; each wave = ONE 16-row m-tile x all 1024 codes
// (64 n-tiles). 3-product Ootomo split bf16 GEMM, enorm in the MFMA C
// operand. Index packed into low 10 mantissa bits; top-2 via min/med3.
// gap < dynamic tau -> exact fp32 rescue. Fused: z_q write (certain rows),
// commitment-loss partial, counts histogram.
__global__ __launch_bounds__(256, 6) void argmin_mfma(const float* __restrict__ z,
                                                      const short* __restrict__ E2,
                                                      const float* __restrict__ enorm,
                                                      const float* __restrict__ E,
                                                      float* __restrict__ out_idx_f,
                                                      float* __restrict__ counts8,
                                                      int* __restrict__ ambig_cnt,
                                                      int* __restrict__ ambig,
                                                      float* __restrict__ loss_ws,
                                                      float* __restrict__ zq) {
    int tid = threadIdx.x;
    int w = tid >> 6, lane = tid & 63;
    int c = lane & 15, q = lane >> 4;
    int mbase = blockIdx.x * 64 + w * 16;

    // A-frag: lane (c,q) loads row mbase+c, dims [q*8, q*8+8) and [32+q*8, ...)
    bf16x8 a[4];   // 0:hi d0-31, 1:hi d32-63, 2:lo d0-31, 3:lo d32-63
    float zn;
    {
        const float* zp = z + (size_t)(mbase + c) * DIM;
        float4 v0 = *(const float4*)(zp + q * 8);
        float4 v1 = *(const float4*)(zp + q * 8 + 4);
        float4 v2 = *(const float4*)(zp + 32 + q * 8);
        float4 v3 = *(const float4*)(zp + 32 + q * 8 + 4);
        float f[16];
        f[0]=v0.x; f[1]=v0.y; f[2]=v0.z; f[3]=v0.w;
        f[4]=v1.x; f[5]=v1.y; f[6]=v1.z; f[7]=v1.w;
        f[8]=v2.x; f[9]=v2.y; f[10]=v2.z; f[11]=v2.w;
        f[12]=v3.x; f[13]=v3.y; f[14]=v3.z; f[15]=v3.w;
        zn = 0.f;
#pragma unroll
        for (int j = 0; j < 16; ++j) zn += f[j] * f[j];
        zn += __shfl_xor(zn, 16);
        zn += __shfl_xor(zn, 32);           // full row norm, all quads
#pragma unroll
        for (int j = 0; j < 8; ++j) {
            short h0 = f2bf(f[j]);
            a[0][j] = h0;
            a[2][j] = f2bf(f[j] - bf2f(h0));
            short h1 = f2bf(f[8 + j]);
            a[1][j] = h1;
            a[3][j] = f2bf(f[8 + j] - bf2f(h1));
        }
    }

    float s1[4] = {INFINITY, INFINITY, INFINITY, INFINITY};
    float s2[4] = {INFINITY, INFINITY, INFINITY, INFINITY};

    unsigned vcode = (unsigned)c;
    for (int tile = 0; tile < 64; ++tile) {
        const bf16x8* bp = (const bf16x8*)E2 + ((size_t)(tile * 16 + c) * 16) + q;
        bf16x8 bh0 = bp[0], bh1 = bp[4], bl0 = bp[8], bl1 = bp[12];
        float en = enorm[tile * 16 + c];
        f32x4 acc = {en, en, en, en};
        acc = __builtin_amdgcn_mfma_f32_16x16x32_bf16(a[0], bl0, acc, 0, 0, 0); // zh.el
        acc = __builtin_amdgcn_mfma_f32_16x16x32_bf16(a[1], bl1, acc, 0, 0, 0);
        acc = __builtin_amdgcn_mfma_f32_16x16x32_bf16(a[2], bh0, acc, 0, 0, 0); // zl.eh
        acc = __builtin_amdgcn_mfma_f32_16x16x32_bf16(a[3], bh1, acc, 0, 0, 0);
        acc = __builtin_amdgcn_mfma_f32_16x16x32_bf16(a[0], bh0, acc, 0, 0, 0); // zh.eh
        acc = __builtin_amdgcn_mfma_f32_16x16x32_bf16(a[1], bh1, acc, 0, 0, 0);
#pragma unroll
        for (int i = 0; i < 4; ++i) {
            float sp = __uint_as_float(
                (__float_as_uint(acc[i]) & 0xFFFFFC00u) | vcode);
            float ns2 = __builtin_amdgcn_fmed3f(s1[i], s2[i], sp);
            s1[i] = fminf(s1[i], sp);
            s2[i] = ns2;
        }
        vcode += 16;
    }

    // merge the 16 col-lanes (packed values carry the index)
#pragma unroll
    for (int off = 1; off < 16; off <<= 1) {
#pragma unroll
        for (int i = 0; i < 4; ++i) {
            float os1 = __shfl_xor(s1[i], off);
            float os2 = __shfl_xor(s2[i], off);
            float ns1 = fminf(s1[i], os1);
            s2[i] = fminf(fmaxf(s1[i], os1), fminf(s2[i], os2));
            s1[i] = ns1;
        }
    }

    // slot i on c==0 lanes = row mbase + q*4 + i; its znorm lives at lane q*4+i
    float znr[4];
#pragma unroll
    for (int i = 0; i < 4; ++i) znr[i] = __shfl(zn, q * 4 + i);

    __shared__ float lred[16];
    int code_s[4], flag_s[4];
    {
        float lsum = 0.f;
        if (c == 0) {
#pragma unroll
            for (int i = 0; i < 4; ++i) {
                int row = mbase + q * 4 + i;
                unsigned b1 = __float_as_uint(s1[i]);
                int code = (int)(b1 & 1023u);
                code_s[i] = code;
                out_idx_f[row] = (float)code;
                float s1v = __uint_as_float(b1 & 0xFFFFFC00u);
                float gap = s2[i] - s1[i];
                float tau = 0.008f + 8e-4f * (fabsf(s1[i]) + fabsf(s2[i]));
                if (gap >= tau) {
                    flag_s[i] = 1;
                    atomicAdd(&counts8[(((unsigned)row >> 8) & 7) * K_CODES + code], 1.0f);
                    lsum += znr[i] + s1v;
                } else {
                    flag_s[i] = 0;
                    int p = atomicAdd(ambig_cnt, 1);
                    ambig[p] = row;
                }
            }
            lred[w * 4 + q] = lsum;
        }
    }
    __syncthreads();
    if (tid == 0) {
        float tot = 0.f;
#pragma unroll
        for (int i = 0; i < 16; ++i) tot += lred[i];
        atomicAdd(loss_ws, tot);
    }

    // fused z_q write for certain rows: wave-broadcast code, coalesced 256B
#pragma unroll
    for (int r = 0; r < 16; ++r) {
        int holder = (r >> 2) << 4;           // c==0 lane of quad r>>2
        int code = __shfl(code_s[r & 3], holder);
        int fl   = __shfl(flag_s[r & 3], holder);
        if (fl)
            zq[(size_t)(mbase + r) * DIM + lane] = E[(size_t)code * DIM + lane];
    }
}

// Wave per 2 ambiguous rows: exact fp32 rescore over all K codes; writes
// idx + z_q + loss for those rows.
__global__ __launch_bounds__(256) void rescue_kernel(const float* __restrict__ z,
                                                     const float* __restrict__ E,
                                                     const float* __restrict__ enorm,
                                                     const int* __restrict__ ambig_cnt,
                                                     const int* __restrict__ ambig,
                                                     float* __restrict__ out_idx_f,
                                                     float* __restrict__ counts8,
                                                     float* __restrict__ loss_ws,
                                                     float* __restrict__ zq) {
    int lane = threadIdx.x & 63;
    int wave = (blockIdx.x * 256 + threadIdx.x) >> 6;
    int nw = gridDim.x * 4;
    int cnt = *ambig_cnt;
    for (int a = 2 * wave; a < cnt; a += 2 * nw) {
        int row0 = ambig[a];
        bool two = (a + 1) < cnt;
        int row1 = two ? ambig[a + 1] : row0;
        const float4* zp0 = (const float4*)(z + (size_t)row0 * DIM);
        const float4* zp1 = (const float4*)(z + (size_t)row1 * DIM);
        float4 zr0[16], zr1[16];
        float zn0 = 0.f, zn1 = 0.f;
#pragma unroll
        for (int i = 0; i < 16; ++i) {
            float4 u = zp0[i], v = zp1[i];
            zr0[i] = u; zr1[i] = v;
            zn0 += u.x * u.x + u.y * u.y + u.z * u.z + u.w * u.w;
            zn1 += v.x * v.x + v.y * v.y + v.z * v.z + v.w * v.w;
        }
        float best0 = INFINITY, best1 = INFINITY;
        int bi0 = 0, bi1 = 0;
        for (int j = 0; j < 16; ++j) {
            int code = j * 64 + lane;
            const float4* ep = (const float4*)(E + (size_t)code * DIM);
            float a0 = 0.f, a1 = 0.f, a2 = 0.f, a3 = 0.f;
            float c0 = 0.f, c1 = 0.f, c2 = 0.f, c3 = 0.f;
#pragma unroll
            for (int i = 0; i < 16; ++i) {
                float4 ev = ep[i];
                a0 += zr0[i].x * ev.x; a1 += zr0[i].y * ev.y;
                a2 += zr0[i].z * ev.z; a3 += zr0[i].w * ev.w;
                c0 += zr1[i].x * ev.x; c1 += zr1[i].y * ev.y;
                c2 += zr1[i].z * ev.z; c3 += zr1[i].w * ev.w;
            }
            float en = enorm[code];
            float s0 = en - 2.f * ((a0 + a1) + (a2 + a3));
            float s1 = en - 2.f * ((c0 + c1) + (c2 + c3));
            if (s0 < best0) { best0 = s0; bi0 = code; }
            if (s1 < best1) { best1 = s1; bi1 = code; }
        }
#pragma unroll
        for (int off = 1; off < 64; off <<= 1) {
            float ob = __shfl_xor(best0, off);
            int oi = __shfl_xor(bi0, off);
            if (ob < best0 || (ob == best0 && oi < bi0)) { best0 = ob; bi0 = oi; }
            float ob1 = __shfl_xor(best1, off);
            int oi1 = __shfl_xor(bi1, off);
            if (ob1 < best1 || (ob1 == best1 && oi1 < bi1)) { best1 = ob1; bi1 = oi1; }
        }
        // all lanes know bi0/bi1 after the butterfly
        zq[(size_t)row0 * DIM + lane] = E[(size_t)bi0 * DIM + lane];
        if (two) zq[(size_t)row1 * DIM + lane] = E[(size_t)bi1 * DIM + lane];
        if (lane == 0) {
            out_idx_f[row0] = (float)bi0;
            atomicAdd(&counts8[(((unsigned)row0 >> 8) & 7) * K_CODES + bi0], 1.0f);
            float ladd = zn0 + best0;
            if (two) {
                out_idx_f[row1] = (float)bi1;
                atomicAdd(&counts8[(((unsigned)row1 >> 8) & 7) * K_CODES + bi1], 1.0f);
                ladd += zn1 + best1;
            }
            atomicAdd(loss_ws, ladd);
        }
    }
}

// counts8 -> ncs, n, cs, sharded cursors. Shfl-scan, 2 barriers.
__global__ __launch_bounds__(1024) void scan_kernel(const float* __restrict__ cluster_size,
                                                    const float* __restrict__ counts8,
                                                    float* __restrict__ ncs_out,
                                                    float* __restrict__ cs_ws,
                                                    int* __restrict__ cursor8) {
    int k = threadIdx.x;
    int lane = k & 63, wv = k >> 6;
    float c8[8];
    float cnt = 0.f;
#pragma unroll
    for (int s = 0; s < 8; ++s) { c8[s] = counts8[s * K_CODES + k]; cnt += c8[s]; }
    float ncs = cluster_size[k] * DECAYF + OMDF * cnt;
    ncs_out[k] = ncs;

    int v = (int)cnt;
    int vs = v;
#pragma unroll
    for (int off = 1; off < 64; off <<= 1) {
        int o = __shfl_up(vs, off, 64);
        if (lane >= off) vs += o;
    }
    float fs = ncs;
#pragma unroll
    for (int off = 1; off < 64; off <<= 1) fs += __shfl_xor(fs, off);

    __shared__ int wtot[16];
    __shared__ float ftot[16];
    __shared__ float nsh;
    if (lane == 63) wtot[wv] = vs;
    if (lane == 0) ftot[wv] = fs;
    __syncthreads();
    if (k == 0) {
        int run = 0; float fn = 0.f;
#pragma unroll
        for (int i = 0; i < 16; ++i) {
            int t = wtot[i]; wtot[i] = run; run += t;
            fn += ftot[i];
        }
        nsh = fn;
    }
    __syncthreads();
    float n = nsh;
    cs_ws[k] = (ncs + EPSF) / (n + (float)K_CODES * EPSF) * n;

    int excl = vs - v + wtot[wv];
    int run = excl;
#pragma unroll
    for (int s = 0; s < 8; ++s) { cursor8[s * K_CODES + k] = run; run += (int)c8[s]; }
}

// order[p] = code<<17 | row
__global__ __launch_bounds__(256) void scatter_kernel(const float* __restrict__ idx_f,
                                                      int* __restrict__ cursor8,
                                                      int* __restrict__ order) {
    int row = blockIdx.x * 256 + threadIdx.x;
    int k = (int)idx_f[row];
    int shard = ((unsigned)row >> 8) & 7;
    int p = atomicAdd(&cursor8[shard * K_CODES + k], 1);
    order[p] = (k << 17) | row;
}

// Work-partitioned segment sum: each wave owns 64 entries of the sorted
// order array; lane = dim; run-length accumulate, flush per code-run.
__global__ __launch_bounds__(256) void segsum_kernel(const float* __restrict__ z,
                                                     const int* __restrict__ order,
                                                     float* __restrict__ embsum) {
    int lane = threadIdx.x & 63;
    int w = threadIdx.x >> 6;
    int wave = blockIdx.x * 4 + w;
    int base = wave * 64;

    int my = order[base + lane];

    int cur = __shfl(my, 0, 64) >> 17;
    float sum = 0.f;
#pragma unroll 8
    for (int i = 0; i < 64; ++i) {
        int p = __shfl(my, i, 64);
        int row = p & 0x1FFFF;
        int code = p >> 17;
        float v = z[(size_t)row * DIM + lane];
        if (code != cur) {
            atomicAdd(&embsum[(size_t)cur * DIM + lane], sum);
            sum = 0.f;
            cur = code;
        }
        sum += v;
    }
    atomicAdd(&embsum[(size_t)cur * DIM + lane], sum);
}

// EMA epilogue over [K, D] + loss finalize.
__global__ __launch_bounds__(256) void ema2_kernel(const float* __restrict__ ema,
                                                   const float* __restrict__ embsum,
                                                   const float* __restrict__ cs_ws,
                                                   const float* __restrict__ loss_ws,
                                                   float* __restrict__ newema_out,
                                                   float* __restrict__ newemb_out,
                                                   float* __restrict__ loss_out) {
    int i = blockIdx.x * 256 + threadIdx.x;
    float nes = ema[i] * DECAYF + OMDF * embsum[i];
    newema_out[i] = nes;
    newemb_out[i] = nes / cs_ws[i >> 6];
    if (i == 0)
        loss_out[0] = loss_ws[0] * (1.0f / ((float)N_PTS * (float)DIM));
}

extern "C" void kernel_launch(void* const* d_in, const int* in_sizes, int n_in,
                              void* d_out, int out_size, void* d_ws, size_t ws_size,
                              hipStream_t stream) {
    const float* z            = (const float*)d_in[0];
    const float* E            = (const float*)d_in[1];
    const float* cluster_size = (const float*)d_in[2];
    const float* ema          = (const float*)d_in[3];
    float* out = (float*)d_out;
    float* ws  = (float*)d_ws;

    econv_kernel<<<36, 256, 0, stream>>>(E, (short*)(ws + WS_E2),
                                         ws + WS_ENORM, ws);

    argmin_mfma<<<N_PTS / 64, 256, 0, stream>>>(z, (const short*)(ws + WS_E2),
                                                ws + WS_ENORM, E,
                                                out + OUT_IDX,
                                                ws + WS_C8,
                                                (int*)(ws + WS_ACNT),
                                                (int*)(ws + WS_AMBIG),
                                                ws + WS_LOSS,
                                                out + OUT_ZQ);

    rescue_kernel<<<512, 256, 0, stream>>>(z, E, ws + WS_ENORM,
                                           (const int*)(ws + WS_ACNT),
                                           (const int*)(ws + WS_AMBIG),
                                           out + OUT_IDX,
                                           ws + WS_C8,
                                           ws + WS_LOSS,
                                           out + OUT_ZQ);

    scan_kernel<<<1, 1024, 0, stream>>>(cluster_size, ws + WS_C8,
                                        out + OUT_NEWCS, ws + WS_CS,
                                        (int*)(ws + WS_CUR8));

    scatter_kernel<<<N_PTS / 256, 256, 0, stream>>>(out + OUT_IDX,
                                                    (int*)(ws + WS_CUR8),
                                                    (int*)(ws + WS_ORDER));

    segsum_kernel<<<N_PTS / 256, 256, 0, stream>>>(z,
                                                   (const int*)(ws + WS_ORDER),
                                                   ws + WS_EMBSUM);

    ema2_kernel<<<K_CODES * DIM / 256, 256, 0, stream>>>(ema, ws + WS_EMBSUM,
                                                         ws + WS_CS,
                                                         ws + WS_LOSS,
                                                         out + OUT_NEWEMA,
                                                         out + OUT_NEWEMB,
                                                         out + OUT_LOSS);
}

// Round 9
// 351.822 us; speedup vs baseline: 1.2279x; 1.2279x over previous
//
#include <hip/hip_runtime.h>

#define N_PTS 131072
#define K_CODES 1024
#define DIM 64
#define DECAYF 0.99f
#define OMDF 0.01f
#define EPSF 1e-5f

// ---- d_out layout (float elements, reference return order) ----
#define OUT_ZQ      0                  // [N, D]
#define OUT_LOSS    8388608            // scalar
#define OUT_IDX     8388609            // [N] (indices as floats)
#define OUT_NEWEMB  8519681            // [K, D]
#define OUT_NEWCS   8585217            // [K]
#define OUT_NEWEMA  8586241            // [K, D]

// ---- ws layout (float elements) ----
// zero region [0, WS_ZERO_END) zeroed by econv blocks 4..35
#define WS_C8       0                  // 8*K floats (sharded counts)
#define WS_LOSS     8192               // 16 floats
#define WS_EMBSUM   8208               // K*D floats (atomic accumulator)
#define WS_ZERO_END 73744
#define WS_ENORM    73744              // K floats
#define WS_CS       74768              // K floats
#define WS_E2       75792              // K*128 bf16 (32768 float slots); byte off %16==0

typedef __attribute__((ext_vector_type(8))) short bf16x8;
typedef __attribute__((ext_vector_type(4))) float f32x4;

static __device__ inline short f2bf(float f) {
    unsigned u = __float_as_uint(f);
    unsigned r = (u + 0x7fffu + ((u >> 16) & 1u)) >> 16;   // RNE
    return (short)r;
}
static __device__ inline float bf2f(short h) {
    return __uint_as_float(((unsigned)(unsigned short)h) << 16);
}

// blocks 0..3: E -> E2 = bf16 hi/lo split of (-2E), [hi(64)|lo(64)]; enorm.
// blocks 4..35: zero the ws counter/accumulator region.
__global__ __launch_bounds__(256) void econv_kernel(const float* __restrict__ E,
                                                    short* __restrict__ E2,
                                                    float* __restrict__ enorm,
                                                    float* __restrict__ ws0) {
    if (blockIdx.x >= 4) {
        for (int i = (blockIdx.x - 4) * 256 + threadIdx.x; i < WS_ZERO_END;
             i += 32 * 256)
            ws0[i] = 0.f;
        return;
    }
    int k = blockIdx.x * 256 + threadIdx.x;
    const float* ep = E + (size_t)k * DIM;
    short* o = E2 + (size_t)k * 128;
    float s = 0.f;
#pragma unroll
    for (int d = 0; d < 64; ++d) {
        float f = ep[d];
        s += f * f;
        float m = -2.f * f;
        short h = f2bf(m);
        o[d] = h;
        o[64 + d] = f2bf(m - bf2f(h));
    }
    enorm[k] = s;
}

// 512 blocks x 256 thr; wave = 64 rows (4 m-tiles, 4 independent MFMA
// chains) x all 1024 codes (64 n-tiles). 3-product Ootomo split bf16 GEMM,
// enorm rides in the MFMA C operand. Code packed into low 10 mantissa bits;
// top-2 via min/med3. gap < dynamic tau -> IN-BLOCK exact fp32 rescue.
// Fully fused: idx, counts, commitment loss, z_q writes (all rows).
__global__ __launch_bounds__(256) void argmin_mfma(const float* __restrict__ z,
                                                   const short* __restrict__ E2,
                                                   const float* __restrict__ enorm,
                                                   const float* __restrict__ E,
                                                   float* __restrict__ out_idx_f,
                                                   float* __restrict__ counts8,
                                                   float* __restrict__ loss_ws,
                                                   float* __restrict__ zq) {
    __shared__ int s_info[256];    // code | (ambig<<10) per row-in-block
    __shared__ int s_alist[256];
    __shared__ int s_acnt;
    __shared__ float lred[16];

    int tid = threadIdx.x;
    int w = tid >> 6, lane = tid & 63;
    int c = lane & 15, q = lane >> 4;
    int rbase = blockIdx.x * 256;
    int mbase = rbase + w * 64;

    if (tid == 0) s_acnt = 0;
    __syncthreads();

    // A-frags, hi/lo split. A[m=lane&15][k=q*8+j].
    bf16x8 a[4][4];   // [t][p]: p= 0:hi d0-31, 1:hi d32-63, 2:lo d0-31, 3:lo d32-63
    float znorm_t[4];
#pragma unroll
    for (int t = 0; t < 4; ++t) {
        const float* zp = z + (size_t)(mbase + t * 16 + c) * DIM;
        const float4* z4a = (const float4*)(zp + q * 8);
        const float4* z4b = (const float4*)(zp + 32 + q * 8);
        float f[16];
        float4 v0 = z4a[0], v1 = z4a[1], v2 = z4b[0], v3 = z4b[1];
        f[0]=v0.x; f[1]=v0.y; f[2]=v0.z; f[3]=v0.w;
        f[4]=v1.x; f[5]=v1.y; f[6]=v1.z; f[7]=v1.w;
        f[8]=v2.x; f[9]=v2.y; f[10]=v2.z; f[11]=v2.w;
        f[12]=v3.x; f[13]=v3.y; f[14]=v3.z; f[15]=v3.w;
        float zn = 0.f;
#pragma unroll
        for (int j = 0; j < 16; ++j) zn += f[j] * f[j];
#pragma unroll
        for (int off = 16; off < 64; off <<= 1) zn += __shfl_xor(zn, off);
        znorm_t[t] = zn;
#pragma unroll
        for (int j = 0; j < 8; ++j) {
            short h0 = f2bf(f[j]);
            a[t][0][j] = h0;
            a[t][2][j] = f2bf(f[j] - bf2f(h0));
            short h1 = f2bf(f[8 + j]);
            a[t][1][j] = h1;
            a[t][3][j] = f2bf(f[8 + j] - bf2f(h1));
        }
    }

    float s1[16], s2[16];
#pragma unroll
    for (int idx = 0; idx < 16; ++idx) { s1[idx] = INFINITY; s2[idx] = INFINITY; }

    unsigned vcode = (unsigned)c;
    for (int tile = 0; tile < 64; ++tile) {
        const bf16x8* bp = (const bf16x8*)E2 + ((size_t)(tile * 16 + c) * 16) + q;
        bf16x8 bh0 = bp[0], bh1 = bp[4], bl0 = bp[8], bl1 = bp[12];
        float en = enorm[tile * 16 + c];
#pragma unroll
        for (int t = 0; t < 4; ++t) {
            f32x4 acc = {en, en, en, en};
            acc = __builtin_amdgcn_mfma_f32_16x16x32_bf16(a[t][0], bl0, acc, 0, 0, 0); // zh.el
            acc = __builtin_amdgcn_mfma_f32_16x16x32_bf16(a[t][1], bl1, acc, 0, 0, 0);
            acc = __builtin_amdgcn_mfma_f32_16x16x32_bf16(a[t][2], bh0, acc, 0, 0, 0); // zl.eh
            acc = __builtin_amdgcn_mfma_f32_16x16x32_bf16(a[t][3], bh1, acc, 0, 0, 0);
            acc = __builtin_amdgcn_mfma_f32_16x16x32_bf16(a[t][0], bh0, acc, 0, 0, 0); // zh.eh
            acc = __builtin_amdgcn_mfma_f32_16x16x32_bf16(a[t][1], bh1, acc, 0, 0, 0);
#pragma unroll
            for (int i = 0; i < 4; ++i) {
                float sp = __uint_as_float(
                    (__float_as_uint(acc[i]) & 0xFFFFFC00u) | vcode);
                int idx = t * 4 + i;
                float ns2 = __builtin_amdgcn_fmed3f(s1[idx], s2[idx], sp);
                s1[idx] = fminf(s1[idx], sp);
                s2[idx] = ns2;
            }
        }
        vcode += 16;
    }

    // merge the 16 col-lanes per quad (packed values carry the index)
#pragma unroll
    for (int off = 1; off < 16; off <<= 1) {
#pragma unroll
        for (int idx = 0; idx < 16; ++idx) {
            float os1 = __shfl_xor(s1[idx], off);
            float os2 = __shfl_xor(s2[idx], off);
            float ns1 = fminf(s1[idx], os1);
            s2[idx] = fminf(fmaxf(s1[idx], os1), fminf(s2[idx], os2));
            s1[idx] = ns1;
        }
    }

    // znorm transport: slot (t,i) on c==0 lane needs row mbase+t*16+q*4+i
    float znr[16];
#pragma unroll
    for (int t = 0; t < 4; ++t)
#pragma unroll
        for (int i = 0; i < 4; ++i)
            znr[t * 4 + i] = __shfl(znorm_t[t], (q << 4) | (q * 4 + i), 64);

    {
        float lsum = 0.f;
        if (c == 0) {
#pragma unroll
            for (int idx = 0; idx < 16; ++idx) {
                int t = idx >> 2, i = idx & 3;
                int rib = w * 64 + t * 16 + q * 4 + i;   // row in block
                int row = rbase + rib;
                unsigned b1 = __float_as_uint(s1[idx]);
                int code = (int)(b1 & 1023u);
                float s1v = __uint_as_float(b1 & 0xFFFFFC00u);
                float gap = s2[idx] - s1[idx];
                float tau = 0.008f + 8e-4f * (fabsf(s1[idx]) + fabsf(s2[idx]));
                if (gap >= tau) {
                    s_info[rib] = code;
                    out_idx_f[row] = (float)code;
                    atomicAdd(&counts8[(((unsigned)row >> 8) & 7) * K_CODES + code], 1.0f);
                    lsum += znr[idx] + s1v;
                } else {
                    s_info[rib] = code | 1024;
                    int p = atomicAdd(&s_acnt, 1);
                    s_alist[p] = rib;
                }
            }
            lred[w * 4 + q] = lsum;
        }
    }
    __syncthreads();

    if (tid == 0) {
        float tot = 0.f;
#pragma unroll
        for (int i = 0; i < 16; ++i) tot += lred[i];
        atomicAdd(loss_ws, tot);
    }

    // fused z_q write for certain rows (256 rows x 64 dims, coalesced)
    for (int it = 0; it < 64; ++it) {
        int le = it * 256 + tid;
        int rl = le >> 6, d = le & 63;
        int info = s_info[rl];
        if (!(info & 1024))
            zq[(size_t)(rbase + rl) * DIM + d] = E[(size_t)(info & 1023) * DIM + d];
    }

    // in-block exact fp32 rescue: wave w handles ambig entries w, w+4, ...
    int acnt = s_acnt;
    for (int aI = w; aI < acnt; aI += 4) {
        int rib = s_alist[aI];
        int row = rbase + rib;
        const float4* zp = (const float4*)(z + (size_t)row * DIM);
        float4 zr[16];
        float zn2 = 0.f;
#pragma unroll
        for (int i = 0; i < 16; ++i) {
            float4 u = zp[i];
            zr[i] = u;
            zn2 += u.x * u.x + u.y * u.y + u.z * u.z + u.w * u.w;
        }
        float best = INFINITY;
        int bi = 0;
        for (int j = 0; j < 16; ++j) {
            int code = j * 64 + lane;
            const float4* ep = (const float4*)(E + (size_t)code * DIM);
            float a0 = 0.f, a1 = 0.f, a2 = 0.f, a3 = 0.f;
#pragma unroll
            for (int i = 0; i < 16; ++i) {
                float4 ev = ep[i];
                a0 += zr[i].x * ev.x; a1 += zr[i].y * ev.y;
                a2 += zr[i].z * ev.z; a3 += zr[i].w * ev.w;
            }
            float s = enorm[code] - 2.f * ((a0 + a1) + (a2 + a3));
            if (s < best) { best = s; bi = code; }
        }
#pragma unroll
        for (int off = 1; off < 64; off <<= 1) {
            float ob = __shfl_xor(best, off);
            int oi = __shfl_xor(bi, off);
            if (ob < best || (ob == best && oi < bi)) { best = ob; bi = oi; }
        }
        zq[(size_t)row * DIM + lane] = E[(size_t)bi * DIM + lane];
        if (lane == 0) {
            out_idx_f[row] = (float)bi;
            atomicAdd(&counts8[(((unsigned)row >> 8) & 7) * K_CODES + bi], 1.0f);
            atomicAdd(loss_ws, zn2 + best);
        }
    }
}

// Blocks 0..127: LDS-histogram segment sum. Block b owns dim-slice (b&3)
// (16 dims) and row range [(b>>2)*4096, +4096). Accumulate z into a K x 16
// LDS histogram (fp32 LDS atomics), flush once to global embsum.
// Block 128: the tiny scan (ncs, n, cs).
__global__ __launch_bounds__(256) void histsum_kernel(const float* __restrict__ z,
                                                      const float* __restrict__ idx_f,
                                                      const float* __restrict__ cluster_size,
                                                      const float* __restrict__ counts8,
                                                      float* __restrict__ embsum,
                                                      float* __restrict__ ncs_out,
                                                      float* __restrict__ cs_ws) {
    __shared__ float hist[K_CODES * 16];   // 64 KB
    int tid = threadIdx.x;

    if (blockIdx.x == 128) {               // scan block
        float ncs_r[4];
        float part = 0.f;
#pragma unroll
        for (int j = 0; j < 4; ++j) {
            int k = tid * 4 + j;
            float cnt = 0.f;
#pragma unroll
            for (int s = 0; s < 8; ++s) cnt += counts8[s * K_CODES + k];
            float ncs = cluster_size[k] * DECAYF + OMDF * cnt;
            ncs_out[k] = ncs;
            ncs_r[j] = ncs;
            part += ncs;
        }
#pragma unroll
        for (int off = 1; off < 64; off <<= 1) part += __shfl_xor(part, off);
        if ((tid & 63) == 0) hist[tid >> 6] = part;
        __syncthreads();
        float n = hist[0] + hist[1] + hist[2] + hist[3];
#pragma unroll
        for (int j = 0; j < 4; ++j) {
            int k = tid * 4 + j;
            cs_ws[k] = (ncs_r[j] + EPSF) / (n + (float)K_CODES * EPSF) * n;
        }
        return;
    }

    int slice = blockIdx.x & 3;            // dims [slice*16, +16)
    int rbase = (blockIdx.x >> 2) * 4096;

    for (int i = tid; i < K_CODES * 16; i += 256) hist[i] = 0.f;
    __syncthreads();

    int dl = (tid & 3) * 4;                // 0,4,8,12 within slice
    for (int it = 0; it < 64; ++it) {
        int row = rbase + it * 64 + (tid >> 2);
        int code = (int)idx_f[row];
        float4 v = *(const float4*)(z + (size_t)row * DIM + slice * 16 + dl);
        float* h = &hist[code * 16 + dl];
        atomicAdd(&h[0], v.x);
        atomicAdd(&h[1], v.y);
        atomicAdd(&h[2], v.z);
        atomicAdd(&h[3], v.w);
    }
    __syncthreads();

    for (int i = tid; i < K_CODES * 16; i += 256) {
        float v = hist[i];
        if (v != 0.f)
            atomicAdd(&embsum[(size_t)(i >> 4) * DIM + slice * 16 + (i & 15)], v);
    }
}

// EMA epilogue over [K, D] + loss finalize.
__global__ __launch_bounds__(256) void ema2_kernel(const float* __restrict__ ema,
                                                   const float* __restrict__ embsum,
                                                   const float* __restrict__ cs_ws,
                                                   const float* __restrict__ loss_ws,
                                                   float* __restrict__ newema_out,
                                                   float* __restrict__ newemb_out,
                                                   float* __restrict__ loss_out) {
    int i = blockIdx.x * 256 + threadIdx.x;
    float nes = ema[i] * DECAYF + OMDF * embsum[i];
    newema_out[i] = nes;
    newemb_out[i] = nes / cs_ws[i >> 6];
    if (i == 0)
        loss_out[0] = loss_ws[0] * (1.0f / ((float)N_PTS * (float)DIM));
}

extern "C" void kernel_launch(void* const* d_in, const int* in_sizes, int n_in,
                              void* d_out, int out_size, void* d_ws, size_t ws_size,
                              hipStream_t stream) {
    const float* z            = (const float*)d_in[0];
    const float* E            = (const float*)d_in[1];
    const float* cluster_size = (const float*)d_in[2];
    const float* ema          = (const float*)d_in[3];
    float* out = (float*)d_out;
    float* ws  = (float*)d_ws;

    econv_kernel<<<36, 256, 0, stream>>>(E, (short*)(ws + WS_E2),
                                         ws + WS_ENORM, ws);

    argmin_mfma<<<N_PTS / 256, 256, 0, stream>>>(z, (const short*)(ws + WS_E2),
                                                 ws + WS_ENORM, E,
                                                 out + OUT_IDX,
                                                 ws + WS_C8,
                                                 ws + WS_LOSS,
                                                 out + OUT_ZQ);

    histsum_kernel<<<129, 256, 0, stream>>>(z, out + OUT_IDX, cluster_size,
                                            ws + WS_C8,
                                            ws + WS_EMBSUM,
                                            out + OUT_NEWCS,
                                            ws + WS_CS);

    ema2_kernel<<<K_CODES * DIM / 256, 256, 0, stream>>>(ema, ws + WS_EMBSUM,
                                                         ws + WS_CS,
                                                         ws + WS_LOSS,
                                                         out + OUT_NEWEMA,
                                                         out + OUT_NEWEMB,
                                                         out + OUT_LOSS);
}